// Round 6
// baseline (126.350 us; speedup 1.0000x reference)
//
#include <hip/hip_runtime.h>
#include <math.h>

#define N0 200000
#define N1 1024
#define N2 256
#define N3 32
#define NE0 2048000
#define NE1 262144
#define NE2 8192
#define BATCH 32
#define NCLS 10
#define NB 4            // src-range buckets for gather0 (XCD L2 partitioning)
#define SRC_PER_B 50000 // N0 / NB

typedef _Float16 h2 __attribute__((ext_vector_type(2)));
typedef _Float16 h8 __attribute__((ext_vector_type(8)));

__device__ __forceinline__ int lower_bound_i(const int* __restrict__ a, int n, int key) {
    int lo = 0, hi = n;
    while (lo < hi) {
        int mid = (lo + hi) >> 1;
        if (a[mid] < key) lo = mid + 1; else hi = mid;
    }
    return lo;
}

// x (32, 200000) fp32 -> xt (200000, 32) fp16 rows (64 B each), LDS tiled.
__global__ __launch_bounds__(256) void k_transpose(const float* __restrict__ x,
                                                   h2* __restrict__ xt) {
    __shared__ float tile[32][65];
    const int col0 = blockIdx.x * 64;
    const int tid = threadIdx.x;
    const int c = tid & 63, r0 = tid >> 6;       // 4 row-lanes
    #pragma unroll
    for (int r = r0; r < 32; r += 4) {
        int col = col0 + c;
        tile[r][c] = (col < N0) ? x[r * N0 + col] : 0.f;
    }
    __syncthreads();
    const int bb = (tid & 15) * 2, c0 = tid >> 4; // 16 col-lanes, 2 batch rows/thread
    #pragma unroll
    for (int cc = c0; cc < 64; cc += 16) {
        int col = col0 + cc;
        if (col < N0) {
            h2 v;
            v[0] = (_Float16)tile[bb][cc];
            v[1] = (_Float16)tile[bb + 1][cc];
            xt[col * 16 + (bb >> 1)] = v;
        }
    }
}

// Layer-0 gather, src-range bucketed for XCD-L2 residency.
// Block (n, b): b = blockIdx&3 (lands on XCDs {b, b+4} under round-robin
// blockIdx->XCD), n = blockIdx>>2. Scans dst-segment n's src list and
// accumulates only rows with src in bucket b's 50000-wide range, so each
// XCD's L2 only ever holds one 3.2 MB sub-table -> gathers become L2 hits.
// Deterministic: fixed per-block edge order, no atomics.
__global__ __launch_bounds__(256) void k_gather0b(const h8* __restrict__ table,
                                                  const int* __restrict__ src,
                                                  const int* __restrict__ dst,
                                                  float* __restrict__ part) {
    const int b = blockIdx.x & (NB - 1);
    const int n = blockIdx.x >> 2;
    const int e0 = lower_bound_i(dst, NE0, n);
    const int e1 = lower_bound_i(dst, NE0, n + 1);
    const int tid = threadIdx.x;
    const int b4 = tid & 3;       // which 16B chunk of the 64B row
    const int g  = tid >> 2;      // 64 edge groups
    const int slo = b * SRC_PER_B;
    const int shi = slo + SRC_PER_B;
    float acc[8] = {0.f, 0.f, 0.f, 0.f, 0.f, 0.f, 0.f, 0.f};
    for (int e = e0 + g; e < e1; e += 64) {
        int s = __builtin_nontemporal_load(src + e);
        if (s >= slo && s < shi) {
            h8 v = table[s * 4 + b4];
            #pragma unroll
            for (int i = 0; i < 8; ++i) acc[i] += (float)v[i];
        }
    }
    __shared__ float red[64][33];
    #pragma unroll
    for (int i = 0; i < 8; ++i) red[g][b4 * 8 + i] = acc[i];
    __syncthreads();
    #pragma unroll
    for (int s = 32; s >= 1; s >>= 1) {
        if (g < s) {
            #pragma unroll
            for (int i = 0; i < 8; ++i)
                red[g][b4 * 8 + i] += red[g + s][b4 * 8 + i];
        }
        __syncthreads();
    }
    if (tid < 32) part[(b * N1 + n) * 32 + tid] = red[0][tid];
}

// Combine NB bucket partials -> fp16 table for gather1.
__global__ __launch_bounds__(256) void k_reduceP(const float* __restrict__ part,
                                                 _Float16* __restrict__ out) {
    int i = blockIdx.x * 256 + threadIdx.x;   // [0, N1*32)
    float s = part[i] + part[N1 * 32 + i] + part[2 * N1 * 32 + i] + part[3 * N1 * 32 + i];
    out[i] = (_Float16)s;
}

// Segmented gather-sum over fp16 rows (layers 1-2). 4x unrolled.
__global__ __launch_bounds__(256) void k_gather(const h8* __restrict__ table,
                                                const int* __restrict__ src,
                                                const int* __restrict__ dst,
                                                int nedges,
                                                _Float16* __restrict__ out_h,
                                                float* __restrict__ out_f,
                                                const float* __restrict__ cnt_in,
                                                float* __restrict__ cnt_out,
                                                float* __restrict__ t_out) {
    const int n = blockIdx.x;
    const int e0 = lower_bound_i(dst, nedges, n);
    const int e1 = lower_bound_i(dst, nedges, n + 1);
    const int tid = threadIdx.x;
    const int b4 = tid & 3;
    const int g  = tid >> 2;
    float acc[8] = {0.f, 0.f, 0.f, 0.f, 0.f, 0.f, 0.f, 0.f};
    float tacc = 0.f;
    int e = e0 + g;
    for (; e + 192 < e1; e += 256) {
        int s0 = __builtin_nontemporal_load(src + e);
        int s1 = __builtin_nontemporal_load(src + e + 64);
        int s2 = __builtin_nontemporal_load(src + e + 128);
        int s3 = __builtin_nontemporal_load(src + e + 192);
        h8 v0 = table[s0 * 4 + b4];
        h8 v1 = table[s1 * 4 + b4];
        h8 v2 = table[s2 * 4 + b4];
        h8 v3 = table[s3 * 4 + b4];
        #pragma unroll
        for (int i = 0; i < 8; ++i)
            acc[i] += (float)v0[i] + (float)v1[i] + (float)v2[i] + (float)v3[i];
        if (cnt_in != nullptr && b4 == 0)
            tacc += cnt_in[s0] + cnt_in[s1] + cnt_in[s2] + cnt_in[s3];
    }
    for (; e < e1; e += 64) {
        int s = __builtin_nontemporal_load(src + e);
        h8 v = table[s * 4 + b4];
        #pragma unroll
        for (int i = 0; i < 8; ++i) acc[i] += (float)v[i];
        if (cnt_in != nullptr && b4 == 0) tacc += cnt_in[s];
    }
    __shared__ float red[64][33];
    __shared__ float tred[64];
    #pragma unroll
    for (int i = 0; i < 8; ++i) red[g][b4 * 8 + i] = acc[i];
    if (b4 == 0) tred[g] = tacc;
    __syncthreads();
    #pragma unroll
    for (int s = 32; s >= 1; s >>= 1) {
        if (g < s) {
            #pragma unroll
            for (int i = 0; i < 8; ++i)
                red[g][b4 * 8 + i] += red[g + s][b4 * 8 + i];
            if (b4 == 0) tred[g] += tred[g + s];
        }
        __syncthreads();
    }
    if (tid < 32) {
        float v = red[0][tid];
        if (out_h != nullptr) out_h[n * 32 + tid] = (_Float16)v;
        if (out_f != nullptr) out_f[n * 32 + tid] = v;
    } else if (tid == 32 && cnt_out != nullptr) {
        cnt_out[n] = (float)(e1 - e0);
    } else if (tid == 33 && t_out != nullptr) {
        t_out[n] = tred[0];
    }
}

// Weight algebra + final output. One block per class k (10 blocks, 256 threads).
__global__ __launch_bounds__(256) void k_out(
    const float* __restrict__ V0, const float* __restrict__ g0, const float* __restrict__ b0,
    const float* __restrict__ V1, const float* __restrict__ g1, const float* __restrict__ b1,
    const float* __restrict__ V2, const float* __restrict__ g2, const float* __restrict__ b2,
    const float* __restrict__ Vfc, const float* __restrict__ gfc, const float* __restrict__ bfc,
    const float* __restrict__ S2, const float* __restrict__ T2, const float* __restrict__ cnt2,
    float* __restrict__ out) {
    const int k = blockIdx.x;
    const int tid = threadIdx.x;
    __shared__ float w0[32], u[64], v[64], p[128], q[128], r[128];
    __shared__ float redA[8][32], redB[8][32], redC[8][32], redD[8][32];
    __shared__ float nnred[4];
    __shared__ float M[32];
    __shared__ float scale_s, Kc_s;

    if (tid < 32) {
        float val = V0[tid];
        w0[tid] = g0[tid] * val / fabsf(val);
    }
    __syncthreads();
    if (tid < 64) {
        float nn = 0.f;
        #pragma unroll
        for (int c = 0; c < 32; ++c) { float t = V1[tid * 32 + c]; nn += t * t; }
        float inv = g1[tid] * rsqrtf(nn);
        float su = 0.f, sv = 0.f;
        #pragma unroll
        for (int c = 0; c < 32; ++c) {
            float w = V1[tid * 32 + c] * inv;
            su += w * w0[c]; sv += w * b0[c];
        }
        u[tid] = su; v[tid] = sv;
    }
    __syncthreads();
    if (tid < 128) {
        float nn = 0.f;
        #pragma unroll
        for (int c = 0; c < 64; ++c) { float t = V2[tid * 64 + c]; nn += t * t; }
        float inv = g2[tid] * rsqrtf(nn);
        float sp = 0.f, sq = 0.f, sr = 0.f;
        #pragma unroll
        for (int c = 0; c < 64; ++c) {
            float w = V2[tid * 64 + c] * inv;
            sp += w * u[c]; sq += w * v[c]; sr += w * b1[c];
        }
        p[tid] = sp; q[tid] = sq; r[tid] = sr;
    }
    __syncthreads();

    const int n3 = tid & 31, og = tid >> 5;
    float nn = 0.f, mk = 0.f, mq = 0.f, mr = 0.f, mb = 0.f;
    #pragma unroll
    for (int i = 0; i < 16; ++i) {
        int o = og + 8 * i;
        float w = Vfc[k * 4096 + tid + 256 * i];
        nn += w * w;
        mk += w * p[o]; mq += w * q[o]; mr += w * r[o]; mb += w * b2[o];
    }
    #pragma unroll
    for (int off = 32; off; off >>= 1) nn += __shfl_xor(nn, off);
    if ((tid & 63) == 0) nnred[tid >> 6] = nn;
    redA[og][n3] = mk; redB[og][n3] = mq; redC[og][n3] = mr; redD[og][n3] = mb;
    __syncthreads();
    if (tid == 0) {
        float s = nnred[0] + nnred[1] + nnred[2] + nnred[3];
        scale_s = gfc[k] * rsqrtf(s);
    }
    __syncthreads();
    if (tid < 32) {
        float smk = 0.f, smq = 0.f, smr = 0.f, smb = 0.f;
        #pragma unroll
        for (int i = 0; i < 8; ++i) {
            smk += redA[i][tid]; smq += redB[i][tid];
            smr += redC[i][tid]; smb += redD[i][tid];
        }
        float scale = scale_s;
        M[tid] = scale * smk;
        float kcp = scale * (smq * T2[tid] + smr * cnt2[tid] + smb);
        #pragma unroll
        for (int off = 16; off; off >>= 1) kcp += __shfl_xor(kcp, off);
        if (tid == 0) Kc_s = kcp + bfc[k];
    }
    __syncthreads();
    if (tid < 32) {
        int b = tid;
        float s = 0.f;
        #pragma unroll
        for (int n = 0; n < 32; ++n) s += M[n] * S2[n * 32 + b];
        out[b * NCLS + k] = s + Kc_s;
    }
}

extern "C" void kernel_launch(void* const* d_in, const int* in_sizes, int n_in,
                              void* d_out, int out_size, void* d_ws, size_t ws_size,
                              hipStream_t stream) {
    const float* x   = (const float*)d_in[0];
    const int* src0  = (const int*)d_in[1];
    const int* dst0  = (const int*)d_in[2];
    const int* src1  = (const int*)d_in[3];
    const int* dst1  = (const int*)d_in[4];
    const int* src2  = (const int*)d_in[5];
    const int* dst2  = (const int*)d_in[6];
    const float* V0  = (const float*)d_in[7];
    const float* g0  = (const float*)d_in[8];
    const float* b0  = (const float*)d_in[9];
    const float* V1  = (const float*)d_in[10];
    const float* g1  = (const float*)d_in[11];
    const float* b1  = (const float*)d_in[12];
    const float* V2  = (const float*)d_in[13];
    const float* g2  = (const float*)d_in[14];
    const float* b2  = (const float*)d_in[15];
    const float* Vfc = (const float*)d_in[16];
    const float* gfc = (const float*)d_in[17];
    const float* bfc = (const float*)d_in[18];

    char* ws = (char*)d_ws;
    _Float16* xt  = (_Float16*)(ws);                 // 200000*32*2 = 12,800,000 B
    float* P0p    = (float*)(ws + 12800000);         // NB*1024*32*4 = 524,288 B
    _Float16* P0h = (_Float16*)(ws + 13324288);      // 1024*32*2   = 65,536 B
    _Float16* S1h = (_Float16*)(ws + 13389824);      // 256*32*2    = 16,384 B
    float* cnt1   = (float*)(ws + 13406208);         // 256*4       = 1,024 B
    float* S2     = (float*)(ws + 13407232);         // 32*32*4     = 4,096 B
    float* T2     = (float*)(ws + 13411328);         // 32*4        = 128 B
    float* cnt2   = (float*)(ws + 13411456);         // 32*4        = 128 B

    k_transpose<<<(N0 + 63) / 64, 256, 0, stream>>>(x, (h2*)xt);
    k_gather0b<<<N1 * NB, 256, 0, stream>>>((const h8*)xt, src0, dst0, P0p);
    k_reduceP<<<(N1 * 32) / 256, 256, 0, stream>>>(P0p, P0h);
    k_gather<<<N2, 256, 0, stream>>>((const h8*)P0h, src1, dst1, NE1,
                                     S1h, nullptr, nullptr, cnt1, nullptr);
    k_gather<<<N3, 256, 0, stream>>>((const h8*)S1h, src2, dst2, NE2,
                                     nullptr, S2, cnt1, cnt2, T2);
    k_out<<<NCLS, 256, 0, stream>>>(V0, g0, b0, V1, g1, b1, V2, g2, b2,
                                    Vfc, gfc, bfc, S2, T2, cnt2, (float*)d_out);
}

// Round 7
// 83.716 us; speedup vs baseline: 1.5093x; 1.5093x over previous
//
#include <hip/hip_runtime.h>
#include <math.h>

#define N0 200000
#define N1 1024
#define N2 256
#define N3 32
#define NE0 2048000
#define NE1 262144
#define NE2 8192
#define BATCH 32
#define NCLS 10
#define NB 4            // src-range buckets for gather0 (XCD L2 partitioning)
#define SRC_PER_B 50000 // N0 / NB

typedef _Float16 h2 __attribute__((ext_vector_type(2)));
typedef _Float16 h8 __attribute__((ext_vector_type(8)));

__device__ __forceinline__ int lower_bound_i(const int* __restrict__ a, int n, int key) {
    int lo = 0, hi = n;
    while (lo < hi) {
        int mid = (lo + hi) >> 1;
        if (a[mid] < key) lo = mid + 1; else hi = mid;
    }
    return lo;
}

// x (32, 200000) fp32 -> xt (200000, 32) fp16 rows (64 B each), LDS tiled.
__global__ __launch_bounds__(256) void k_transpose(const float* __restrict__ x,
                                                   h2* __restrict__ xt) {
    __shared__ float tile[32][65];
    const int col0 = blockIdx.x * 64;
    const int tid = threadIdx.x;
    const int c = tid & 63, r0 = tid >> 6;       // 4 row-lanes
    #pragma unroll
    for (int r = r0; r < 32; r += 4) {
        int col = col0 + c;
        tile[r][c] = (col < N0) ? x[r * N0 + col] : 0.f;
    }
    __syncthreads();
    const int bb = (tid & 15) * 2, c0 = tid >> 4; // 16 col-lanes, 2 batch rows/thread
    #pragma unroll
    for (int cc = c0; cc < 64; cc += 16) {
        int col = col0 + cc;
        if (col < N0) {
            h2 v;
            v[0] = (_Float16)tile[bb][cc];
            v[1] = (_Float16)tile[bb + 1][cc];
            xt[col * 16 + (bb >> 1)] = v;
        }
    }
}

// Stable 4-way partition of each dst-segment's src list by src bucket.
// One block per segment. Pass 1 counts (LDS atomics, order-independent ints),
// pass 2 scatters with ballot-rank (stable = original edge order preserved
// within each bucket -> deterministic fp summation order downstream).
__global__ __launch_bounds__(256) void k_partition(const int* __restrict__ src,
                                                   const int* __restrict__ dst,
                                                   int* __restrict__ esrc,
                                                   int* __restrict__ bstart) {
    const int n = blockIdx.x;
    const int e0 = lower_bound_i(dst, NE0, n);
    const int e1 = lower_bound_i(dst, NE0, n + 1);
    const int tid = threadIdx.x;
    const int wave = tid >> 6, lane = tid & 63;
    __shared__ int segCnt[NB];
    __shared__ int segBase[NB + 1];
    __shared__ int waveCnt[4][NB];
    __shared__ int cur[NB];
    if (tid < NB) segCnt[tid] = 0;
    __syncthreads();
    // pass 1: per-bucket counts (src rows stay L1-resident for pass 2)
    for (int base = e0; base < e1; base += 256) {
        int e = base + tid;
        if (e < e1) {
            int b = src[e] / SRC_PER_B;
            atomicAdd(&segCnt[b], 1);
        }
    }
    __syncthreads();
    if (tid == 0) {
        int acc = e0;
        #pragma unroll
        for (int b = 0; b < NB; ++b) { segBase[b] = acc; acc += segCnt[b]; }
        segBase[NB] = acc;   // == e1
    }
    __syncthreads();
    if (tid < NB + 1) bstart[n * (NB + 1) + tid] = segBase[tid];
    if (tid < NB) cur[tid] = segBase[tid];
    __syncthreads();
    // pass 2: stable scatter via ballot rank
    for (int base = e0; base < e1; base += 256) {
        int e = base + tid;
        int s = 0, b = -1;
        if (e < e1) { s = src[e]; b = s / SRC_PER_B; }
        unsigned long long m0 = __ballot(b == 0);
        unsigned long long m1 = __ballot(b == 1);
        unsigned long long m2 = __ballot(b == 2);
        unsigned long long m3 = __ballot(b == 3);
        if (lane == 0) {
            waveCnt[wave][0] = __popcll(m0);
            waveCnt[wave][1] = __popcll(m1);
            waveCnt[wave][2] = __popcll(m2);
            waveCnt[wave][3] = __popcll(m3);
        }
        __syncthreads();
        if (b >= 0) {
            unsigned long long msel = (b == 0) ? m0 : (b == 1) ? m1 : (b == 2) ? m2 : m3;
            int rank = __popcll(msel & ((1ull << lane) - 1ull));
            int pw = 0;
            for (int w = 0; w < wave; ++w) pw += waveCnt[w][b];
            esrc[cur[b] + pw + rank] = s;
        }
        __syncthreads();
        if (tid < NB)
            cur[tid] += waveCnt[0][tid] + waveCnt[1][tid] + waveCnt[2][tid] + waveCnt[3][tid];
        __syncthreads();
    }
}

// Layer-0 gather over bucket-partitioned edges. Block (n, b) reads its
// CONTIGUOUS bucket range [bstart[n,b], bstart[n,b+1]) -- no divergence,
// no redundant scan; table slice b (3.2 MB) stays resident in the L2 of
// XCDs {b, b+4} under round-robin blockIdx->XCD. 4x unrolled chains.
__global__ __launch_bounds__(256) void k_gather0s(const h8* __restrict__ table,
                                                  const int* __restrict__ esrc,
                                                  const int* __restrict__ bstart,
                                                  float* __restrict__ part) {
    const int b = blockIdx.x & (NB - 1);
    const int n = blockIdx.x >> 2;
    const int q0 = bstart[n * (NB + 1) + b];
    const int q1 = bstart[n * (NB + 1) + b + 1];
    const int tid = threadIdx.x;
    const int b4 = tid & 3;       // which 16B chunk of the 64B row
    const int g  = tid >> 2;      // 64 edge groups
    float acc[8] = {0.f, 0.f, 0.f, 0.f, 0.f, 0.f, 0.f, 0.f};
    int e = q0 + g;
    for (; e + 192 < q1; e += 256) {
        int s0 = __builtin_nontemporal_load(esrc + e);
        int s1 = __builtin_nontemporal_load(esrc + e + 64);
        int s2 = __builtin_nontemporal_load(esrc + e + 128);
        int s3 = __builtin_nontemporal_load(esrc + e + 192);
        h8 v0 = table[s0 * 4 + b4];
        h8 v1 = table[s1 * 4 + b4];
        h8 v2 = table[s2 * 4 + b4];
        h8 v3 = table[s3 * 4 + b4];
        #pragma unroll
        for (int i = 0; i < 8; ++i)
            acc[i] += (float)v0[i] + (float)v1[i] + (float)v2[i] + (float)v3[i];
    }
    for (; e < q1; e += 64) {
        int s = __builtin_nontemporal_load(esrc + e);
        h8 v = table[s * 4 + b4];
        #pragma unroll
        for (int i = 0; i < 8; ++i) acc[i] += (float)v[i];
    }
    __shared__ float red[64][33];
    #pragma unroll
    for (int i = 0; i < 8; ++i) red[g][b4 * 8 + i] = acc[i];
    __syncthreads();
    #pragma unroll
    for (int s = 32; s >= 1; s >>= 1) {
        if (g < s) {
            #pragma unroll
            for (int i = 0; i < 8; ++i)
                red[g][b4 * 8 + i] += red[g + s][b4 * 8 + i];
        }
        __syncthreads();
    }
    if (tid < 32) part[(b * N1 + n) * 32 + tid] = red[0][tid];
}

// Combine NB bucket partials -> fp16 table for gather1.
__global__ __launch_bounds__(256) void k_reduceP(const float* __restrict__ part,
                                                 _Float16* __restrict__ out) {
    int i = blockIdx.x * 256 + threadIdx.x;   // [0, N1*32)
    float s = part[i] + part[N1 * 32 + i] + part[2 * N1 * 32 + i] + part[3 * N1 * 32 + i];
    out[i] = (_Float16)s;
}

// Segmented gather-sum over fp16 rows (layers 1-2). 4x unrolled.
__global__ __launch_bounds__(256) void k_gather(const h8* __restrict__ table,
                                                const int* __restrict__ src,
                                                const int* __restrict__ dst,
                                                int nedges,
                                                _Float16* __restrict__ out_h,
                                                float* __restrict__ out_f,
                                                const float* __restrict__ cnt_in,
                                                float* __restrict__ cnt_out,
                                                float* __restrict__ t_out) {
    const int n = blockIdx.x;
    const int e0 = lower_bound_i(dst, nedges, n);
    const int e1 = lower_bound_i(dst, nedges, n + 1);
    const int tid = threadIdx.x;
    const int b4 = tid & 3;
    const int g  = tid >> 2;
    float acc[8] = {0.f, 0.f, 0.f, 0.f, 0.f, 0.f, 0.f, 0.f};
    float tacc = 0.f;
    int e = e0 + g;
    for (; e + 192 < e1; e += 256) {
        int s0 = __builtin_nontemporal_load(src + e);
        int s1 = __builtin_nontemporal_load(src + e + 64);
        int s2 = __builtin_nontemporal_load(src + e + 128);
        int s3 = __builtin_nontemporal_load(src + e + 192);
        h8 v0 = table[s0 * 4 + b4];
        h8 v1 = table[s1 * 4 + b4];
        h8 v2 = table[s2 * 4 + b4];
        h8 v3 = table[s3 * 4 + b4];
        #pragma unroll
        for (int i = 0; i < 8; ++i)
            acc[i] += (float)v0[i] + (float)v1[i] + (float)v2[i] + (float)v3[i];
        if (cnt_in != nullptr && b4 == 0)
            tacc += cnt_in[s0] + cnt_in[s1] + cnt_in[s2] + cnt_in[s3];
    }
    for (; e < e1; e += 64) {
        int s = __builtin_nontemporal_load(src + e);
        h8 v = table[s * 4 + b4];
        #pragma unroll
        for (int i = 0; i < 8; ++i) acc[i] += (float)v[i];
        if (cnt_in != nullptr && b4 == 0) tacc += cnt_in[s];
    }
    __shared__ float red[64][33];
    __shared__ float tred[64];
    #pragma unroll
    for (int i = 0; i < 8; ++i) red[g][b4 * 8 + i] = acc[i];
    if (b4 == 0) tred[g] = tacc;
    __syncthreads();
    #pragma unroll
    for (int s = 32; s >= 1; s >>= 1) {
        if (g < s) {
            #pragma unroll
            for (int i = 0; i < 8; ++i)
                red[g][b4 * 8 + i] += red[g + s][b4 * 8 + i];
            if (b4 == 0) tred[g] += tred[g + s];
        }
        __syncthreads();
    }
    if (tid < 32) {
        float v = red[0][tid];
        if (out_h != nullptr) out_h[n * 32 + tid] = (_Float16)v;
        if (out_f != nullptr) out_f[n * 32 + tid] = v;
    } else if (tid == 32 && cnt_out != nullptr) {
        cnt_out[n] = (float)(e1 - e0);
    } else if (tid == 33 && t_out != nullptr) {
        t_out[n] = tred[0];
    }
}

// Weight algebra + final output. One block per class k (10 blocks, 256 threads).
__global__ __launch_bounds__(256) void k_out(
    const float* __restrict__ V0, const float* __restrict__ g0, const float* __restrict__ b0,
    const float* __restrict__ V1, const float* __restrict__ g1, const float* __restrict__ b1,
    const float* __restrict__ V2, const float* __restrict__ g2, const float* __restrict__ b2,
    const float* __restrict__ Vfc, const float* __restrict__ gfc, const float* __restrict__ bfc,
    const float* __restrict__ S2, const float* __restrict__ T2, const float* __restrict__ cnt2,
    float* __restrict__ out) {
    const int k = blockIdx.x;
    const int tid = threadIdx.x;
    __shared__ float w0[32], u[64], v[64], p[128], q[128], r[128];
    __shared__ float redA[8][32], redB[8][32], redC[8][32], redD[8][32];
    __shared__ float nnred[4];
    __shared__ float M[32];
    __shared__ float scale_s, Kc_s;

    if (tid < 32) {
        float val = V0[tid];
        w0[tid] = g0[tid] * val / fabsf(val);
    }
    __syncthreads();
    if (tid < 64) {
        float nn = 0.f;
        #pragma unroll
        for (int c = 0; c < 32; ++c) { float t = V1[tid * 32 + c]; nn += t * t; }
        float inv = g1[tid] * rsqrtf(nn);
        float su = 0.f, sv = 0.f;
        #pragma unroll
        for (int c = 0; c < 32; ++c) {
            float w = V1[tid * 32 + c] * inv;
            su += w * w0[c]; sv += w * b0[c];
        }
        u[tid] = su; v[tid] = sv;
    }
    __syncthreads();
    if (tid < 128) {
        float nn = 0.f;
        #pragma unroll
        for (int c = 0; c < 64; ++c) { float t = V2[tid * 64 + c]; nn += t * t; }
        float inv = g2[tid] * rsqrtf(nn);
        float sp = 0.f, sq = 0.f, sr = 0.f;
        #pragma unroll
        for (int c = 0; c < 64; ++c) {
            float w = V2[tid * 64 + c] * inv;
            sp += w * u[c]; sq += w * v[c]; sr += w * b1[c];
        }
        p[tid] = sp; q[tid] = sq; r[tid] = sr;
    }
    __syncthreads();

    const int n3 = tid & 31, og = tid >> 5;
    float nn = 0.f, mk = 0.f, mq = 0.f, mr = 0.f, mb = 0.f;
    #pragma unroll
    for (int i = 0; i < 16; ++i) {
        int o = og + 8 * i;
        float w = Vfc[k * 4096 + tid + 256 * i];
        nn += w * w;
        mk += w * p[o]; mq += w * q[o]; mr += w * r[o]; mb += w * b2[o];
    }
    #pragma unroll
    for (int off = 32; off; off >>= 1) nn += __shfl_xor(nn, off);
    if ((tid & 63) == 0) nnred[tid >> 6] = nn;
    redA[og][n3] = mk; redB[og][n3] = mq; redC[og][n3] = mr; redD[og][n3] = mb;
    __syncthreads();
    if (tid == 0) {
        float s = nnred[0] + nnred[1] + nnred[2] + nnred[3];
        scale_s = gfc[k] * rsqrtf(s);
    }
    __syncthreads();
    if (tid < 32) {
        float smk = 0.f, smq = 0.f, smr = 0.f, smb = 0.f;
        #pragma unroll
        for (int i = 0; i < 8; ++i) {
            smk += redA[i][tid]; smq += redB[i][tid];
            smr += redC[i][tid]; smb += redD[i][tid];
        }
        float scale = scale_s;
        M[tid] = scale * smk;
        float kcp = scale * (smq * T2[tid] + smr * cnt2[tid] + smb);
        #pragma unroll
        for (int off = 16; off; off >>= 1) kcp += __shfl_xor(kcp, off);
        if (tid == 0) Kc_s = kcp + bfc[k];
    }
    __syncthreads();
    if (tid < 32) {
        int b = tid;
        float s = 0.f;
        #pragma unroll
        for (int n = 0; n < 32; ++n) s += M[n] * S2[n * 32 + b];
        out[b * NCLS + k] = s + Kc_s;
    }
}

extern "C" void kernel_launch(void* const* d_in, const int* in_sizes, int n_in,
                              void* d_out, int out_size, void* d_ws, size_t ws_size,
                              hipStream_t stream) {
    const float* x   = (const float*)d_in[0];
    const int* src0  = (const int*)d_in[1];
    const int* dst0  = (const int*)d_in[2];
    const int* src1  = (const int*)d_in[3];
    const int* dst1  = (const int*)d_in[4];
    const int* src2  = (const int*)d_in[5];
    const int* dst2  = (const int*)d_in[6];
    const float* V0  = (const float*)d_in[7];
    const float* g0  = (const float*)d_in[8];
    const float* b0  = (const float*)d_in[9];
    const float* V1  = (const float*)d_in[10];
    const float* g1  = (const float*)d_in[11];
    const float* b1  = (const float*)d_in[12];
    const float* V2  = (const float*)d_in[13];
    const float* g2  = (const float*)d_in[14];
    const float* b2  = (const float*)d_in[15];
    const float* Vfc = (const float*)d_in[16];
    const float* gfc = (const float*)d_in[17];
    const float* bfc = (const float*)d_in[18];

    char* ws = (char*)d_ws;
    _Float16* xt  = (_Float16*)(ws);                 // 200000*32*2 = 12,800,000 B
    int* esrc     = (int*)(ws + 12800000);           // 2048000*4   = 8,192,000 B
    int* bstart   = (int*)(ws + 20992000);           // 1024*5*4    = 20,480 B
    float* P0p    = (float*)(ws + 21012480);         // NB*1024*32*4 = 524,288 B
    _Float16* P0h = (_Float16*)(ws + 21536768);      // 1024*32*2   = 65,536 B
    _Float16* S1h = (_Float16*)(ws + 21602304);      // 256*32*2    = 16,384 B
    float* cnt1   = (float*)(ws + 21618688);         // 256*4       = 1,024 B
    float* S2     = (float*)(ws + 21619712);         // 32*32*4     = 4,096 B
    float* T2     = (float*)(ws + 21623808);         // 32*4        = 128 B
    float* cnt2   = (float*)(ws + 21623936);         // 32*4        = 128 B

    k_transpose<<<(N0 + 63) / 64, 256, 0, stream>>>(x, (h2*)xt);
    k_partition<<<N1, 256, 0, stream>>>(src0, dst0, esrc, bstart);
    k_gather0s<<<N1 * NB, 256, 0, stream>>>((const h8*)xt, esrc, bstart, P0p);
    k_reduceP<<<(N1 * 32) / 256, 256, 0, stream>>>(P0p, P0h);
    k_gather<<<N2, 256, 0, stream>>>((const h8*)P0h, src1, dst1, NE1,
                                     S1h, nullptr, nullptr, cnt1, nullptr);
    k_gather<<<N3, 256, 0, stream>>>((const h8*)S1h, src2, dst2, NE2,
                                     nullptr, S2, cnt1, cnt2, T2);
    k_out<<<NCLS, 256, 0, stream>>>(V0, g0, b0, V1, g1, b1, V2, g2, b2,
                                    Vfc, gfc, bfc, S2, T2, cnt2, (float*)d_out);
}

// Round 8
// 77.784 us; speedup vs baseline: 1.6244x; 1.0763x over previous
//
#include <hip/hip_runtime.h>
#include <math.h>

#define N0 200000
#define N1 1024
#define N2 256
#define N3 32
#define NE0 2048000
#define NE1 262144
#define NE2 8192
#define BATCH 32
#define NCLS 10
#define NB 4            // src-range buckets for gather0 (XCD L2 partitioning)
#define SRC_PER_B 50000 // N0 / NB

typedef _Float16 h2 __attribute__((ext_vector_type(2)));
typedef _Float16 h8 __attribute__((ext_vector_type(8)));

__device__ __forceinline__ int lower_bound_i(const int* __restrict__ a, int n, int key) {
    int lo = 0, hi = n;
    while (lo < hi) {
        int mid = (lo + hi) >> 1;
        if (a[mid] < key) lo = mid + 1; else hi = mid;
    }
    return lo;
}

// x (32, 200000) fp32 -> xt (200000, 32) fp16 rows (64 B each), LDS tiled.
__global__ __launch_bounds__(256) void k_transpose(const float* __restrict__ x,
                                                   h2* __restrict__ xt) {
    __shared__ float tile[32][65];
    const int col0 = blockIdx.x * 64;
    const int tid = threadIdx.x;
    const int c = tid & 63, r0 = tid >> 6;       // 4 row-lanes
    #pragma unroll
    for (int r = r0; r < 32; r += 4) {
        int col = col0 + c;
        tile[r][c] = (col < N0) ? x[r * N0 + col] : 0.f;
    }
    __syncthreads();
    const int bb = (tid & 15) * 2, c0 = tid >> 4; // 16 col-lanes, 2 batch rows/thread
    #pragma unroll
    for (int cc = c0; cc < 64; cc += 16) {
        int col = col0 + cc;
        if (col < N0) {
            h2 v;
            v[0] = (_Float16)tile[bb][cc];
            v[1] = (_Float16)tile[bb + 1][cc];
            xt[col * 16 + (bb >> 1)] = v;
        }
    }
}

// Segment starts for dst0 (sorted): off[n] = first edge with dst >= n.
// Thread-per-edge streaming pass; replaces per-block binary searches.
__global__ __launch_bounds__(256) void k_bounds(const int* __restrict__ dst,
                                                int* __restrict__ off) {
    int e = blockIdx.x * 256 + threadIdx.x;
    if (e >= NE0) return;
    int d = dst[e];
    int dp = (e == 0) ? -1 : dst[e - 1];
    for (int n = dp + 1; n <= d; ++n) off[n] = e;
    if (e == NE0 - 1) {
        for (int n = d + 1; n <= N1; ++n) off[n] = NE0;
    }
}

// Stable 4-way partition of each dst-segment's src list by src bucket.
// One block (4 waves) per segment; wave w owns quarter w. Ballot-popcount
// counting (no atomics), 2 barriers total, ballot-rank stable scatter with
// register cursors. Deterministic edge order within each bucket.
__global__ __launch_bounds__(256) void k_partition(const int* __restrict__ src,
                                                   const int* __restrict__ off,
                                                   int* __restrict__ esrc,
                                                   int* __restrict__ bstart) {
    const int n = blockIdx.x;
    const int e0 = off[n];
    const int e1 = off[n + 1];
    const int len = e1 - e0;
    const int tid = threadIdx.x;
    const int wave = tid >> 6, lane = tid & 63;
    const int q0 = e0 + (len * wave) / 4;
    const int q1 = e0 + (len * (wave + 1)) / 4;
    __shared__ int wcnt[4][NB];
    __shared__ int wbase[4][NB];

    // phase 1: per-wave bucket counts via ballot (no atomics)
    int c0 = 0, c1 = 0, c2 = 0, c3 = 0;
    for (int base = q0; base < q1; base += 64) {
        int e = base + lane;
        int b = -1;
        if (e < q1) b = src[e] / SRC_PER_B;
        c0 += __popcll(__ballot(b == 0));
        c1 += __popcll(__ballot(b == 1));
        c2 += __popcll(__ballot(b == 2));
        c3 += __popcll(__ballot(b == 3));
    }
    if (lane == 0) { wcnt[wave][0] = c0; wcnt[wave][1] = c1; wcnt[wave][2] = c2; wcnt[wave][3] = c3; }
    __syncthreads();
    if (tid == 0) {
        int acc = e0;
        #pragma unroll
        for (int b = 0; b < NB; ++b) {
            bstart[n * (NB + 1) + b] = acc;
            #pragma unroll
            for (int w = 0; w < 4; ++w) { wbase[w][b] = acc; acc += wcnt[w][b]; }
        }
        bstart[n * (NB + 1) + NB] = acc;   // == e1
    }
    __syncthreads();

    // phase 2: stable scatter, no barriers (cursors are wave-uniform regs)
    int u0 = wbase[wave][0], u1 = wbase[wave][1], u2 = wbase[wave][2], u3 = wbase[wave][3];
    for (int base = q0; base < q1; base += 64) {
        int e = base + lane;
        int s = 0, b = -1;
        if (e < q1) { s = src[e]; b = s / SRC_PER_B; }
        unsigned long long m0 = __ballot(b == 0);
        unsigned long long m1 = __ballot(b == 1);
        unsigned long long m2 = __ballot(b == 2);
        unsigned long long m3 = __ballot(b == 3);
        unsigned long long lt = (1ull << lane) - 1ull;
        if (b == 0)      esrc[u0 + __popcll(m0 & lt)] = s;
        else if (b == 1) esrc[u1 + __popcll(m1 & lt)] = s;
        else if (b == 2) esrc[u2 + __popcll(m2 & lt)] = s;
        else if (b == 3) esrc[u3 + __popcll(m3 & lt)] = s;
        u0 += __popcll(m0); u1 += __popcll(m1); u2 += __popcll(m2); u3 += __popcll(m3);
    }
}

// Layer-0 gather over bucket-partitioned edges. ONE WAVE per (n, b):
// contiguous range, 4x unrolled chains, __shfl_xor butterfly reduction --
// zero barriers, zero LDS. Table slice b (3.2 MB) stays L2-resident on
// XCDs {b, b+4} under round-robin blockIdx->XCD (blockIdx & 3 == b).
__global__ __launch_bounds__(64) void k_gather0s(const h8* __restrict__ table,
                                                 const int* __restrict__ esrc,
                                                 const int* __restrict__ bstart,
                                                 float* __restrict__ part) {
    const int b = blockIdx.x & (NB - 1);
    const int n = blockIdx.x >> 2;
    const int q0 = bstart[n * (NB + 1) + b];
    const int q1 = bstart[n * (NB + 1) + b + 1];
    const int lane = threadIdx.x;
    const int b4 = lane & 3;      // which 16B chunk of the 64B row
    const int g  = lane >> 2;     // 16 edge groups
    float acc[8] = {0.f, 0.f, 0.f, 0.f, 0.f, 0.f, 0.f, 0.f};
    int e = q0 + g;
    for (; e + 48 < q1; e += 64) {
        int s0 = __builtin_nontemporal_load(esrc + e);
        int s1 = __builtin_nontemporal_load(esrc + e + 16);
        int s2 = __builtin_nontemporal_load(esrc + e + 32);
        int s3 = __builtin_nontemporal_load(esrc + e + 48);
        h8 v0 = table[s0 * 4 + b4];
        h8 v1 = table[s1 * 4 + b4];
        h8 v2 = table[s2 * 4 + b4];
        h8 v3 = table[s3 * 4 + b4];
        #pragma unroll
        for (int i = 0; i < 8; ++i)
            acc[i] += (float)v0[i] + (float)v1[i] + (float)v2[i] + (float)v3[i];
    }
    for (; e < q1; e += 16) {
        int s = __builtin_nontemporal_load(esrc + e);
        h8 v = table[s * 4 + b4];
        #pragma unroll
        for (int i = 0; i < 8; ++i) acc[i] += (float)v[i];
    }
    // butterfly across the 16 edge-groups (lane bits 2..5)
    #pragma unroll
    for (int off = 4; off <= 32; off <<= 1) {
        #pragma unroll
        for (int i = 0; i < 8; ++i) acc[i] += __shfl_xor(acc[i], off);
    }
    if (g == 0) {
        float4 lo = make_float4(acc[0], acc[1], acc[2], acc[3]);
        float4 hi = make_float4(acc[4], acc[5], acc[6], acc[7]);
        float4* p4 = reinterpret_cast<float4*>(part + (size_t)(b * N1 + n) * 32 + b4 * 8);
        p4[0] = lo; p4[1] = hi;
    }
}

// Combine NB bucket partials -> fp16 table for gather1.
__global__ __launch_bounds__(256) void k_reduceP(const float* __restrict__ part,
                                                 _Float16* __restrict__ out) {
    int i = blockIdx.x * 256 + threadIdx.x;   // [0, N1*32)
    float s = part[i] + part[N1 * 32 + i] + part[2 * N1 * 32 + i] + part[3 * N1 * 32 + i];
    out[i] = (_Float16)s;
}

// Segmented gather-sum over fp16 rows (layers 1-2). 4x unrolled.
__global__ __launch_bounds__(256) void k_gather(const h8* __restrict__ table,
                                                const int* __restrict__ src,
                                                const int* __restrict__ dst,
                                                int nedges,
                                                _Float16* __restrict__ out_h,
                                                float* __restrict__ out_f,
                                                const float* __restrict__ cnt_in,
                                                float* __restrict__ cnt_out,
                                                float* __restrict__ t_out) {
    const int n = blockIdx.x;
    const int e0 = lower_bound_i(dst, nedges, n);
    const int e1 = lower_bound_i(dst, nedges, n + 1);
    const int tid = threadIdx.x;
    const int b4 = tid & 3;
    const int g  = tid >> 2;
    float acc[8] = {0.f, 0.f, 0.f, 0.f, 0.f, 0.f, 0.f, 0.f};
    float tacc = 0.f;
    int e = e0 + g;
    for (; e + 192 < e1; e += 256) {
        int s0 = __builtin_nontemporal_load(src + e);
        int s1 = __builtin_nontemporal_load(src + e + 64);
        int s2 = __builtin_nontemporal_load(src + e + 128);
        int s3 = __builtin_nontemporal_load(src + e + 192);
        h8 v0 = table[s0 * 4 + b4];
        h8 v1 = table[s1 * 4 + b4];
        h8 v2 = table[s2 * 4 + b4];
        h8 v3 = table[s3 * 4 + b4];
        #pragma unroll
        for (int i = 0; i < 8; ++i)
            acc[i] += (float)v0[i] + (float)v1[i] + (float)v2[i] + (float)v3[i];
        if (cnt_in != nullptr && b4 == 0)
            tacc += cnt_in[s0] + cnt_in[s1] + cnt_in[s2] + cnt_in[s3];
    }
    for (; e < e1; e += 64) {
        int s = __builtin_nontemporal_load(src + e);
        h8 v = table[s * 4 + b4];
        #pragma unroll
        for (int i = 0; i < 8; ++i) acc[i] += (float)v[i];
        if (cnt_in != nullptr && b4 == 0) tacc += cnt_in[s];
    }
    __shared__ float red[64][33];
    __shared__ float tred[64];
    #pragma unroll
    for (int i = 0; i < 8; ++i) red[g][b4 * 8 + i] = acc[i];
    if (b4 == 0) tred[g] = tacc;
    __syncthreads();
    #pragma unroll
    for (int s = 32; s >= 1; s >>= 1) {
        if (g < s) {
            #pragma unroll
            for (int i = 0; i < 8; ++i)
                red[g][b4 * 8 + i] += red[g + s][b4 * 8 + i];
            if (b4 == 0) tred[g] += tred[g + s];
        }
        __syncthreads();
    }
    if (tid < 32) {
        float v = red[0][tid];
        if (out_h != nullptr) out_h[n * 32 + tid] = (_Float16)v;
        if (out_f != nullptr) out_f[n * 32 + tid] = v;
    } else if (tid == 32 && cnt_out != nullptr) {
        cnt_out[n] = (float)(e1 - e0);
    } else if (tid == 33 && t_out != nullptr) {
        t_out[n] = tred[0];
    }
}

// Weight algebra + final output. One block per class k (10 blocks, 256 threads).
__global__ __launch_bounds__(256) void k_out(
    const float* __restrict__ V0, const float* __restrict__ g0, const float* __restrict__ b0,
    const float* __restrict__ V1, const float* __restrict__ g1, const float* __restrict__ b1,
    const float* __restrict__ V2, const float* __restrict__ g2, const float* __restrict__ b2,
    const float* __restrict__ Vfc, const float* __restrict__ gfc, const float* __restrict__ bfc,
    const float* __restrict__ S2, const float* __restrict__ T2, const float* __restrict__ cnt2,
    float* __restrict__ out) {
    const int k = blockIdx.x;
    const int tid = threadIdx.x;
    __shared__ float w0[32], u[64], v[64], p[128], q[128], r[128];
    __shared__ float redA[8][32], redB[8][32], redC[8][32], redD[8][32];
    __shared__ float nnred[4];
    __shared__ float M[32];
    __shared__ float scale_s, Kc_s;

    if (tid < 32) {
        float val = V0[tid];
        w0[tid] = g0[tid] * val / fabsf(val);
    }
    __syncthreads();
    if (tid < 64) {
        float nn = 0.f;
        #pragma unroll
        for (int c = 0; c < 32; ++c) { float t = V1[tid * 32 + c]; nn += t * t; }
        float inv = g1[tid] * rsqrtf(nn);
        float su = 0.f, sv = 0.f;
        #pragma unroll
        for (int c = 0; c < 32; ++c) {
            float w = V1[tid * 32 + c] * inv;
            su += w * w0[c]; sv += w * b0[c];
        }
        u[tid] = su; v[tid] = sv;
    }
    __syncthreads();
    if (tid < 128) {
        float nn = 0.f;
        #pragma unroll
        for (int c = 0; c < 64; ++c) { float t = V2[tid * 64 + c]; nn += t * t; }
        float inv = g2[tid] * rsqrtf(nn);
        float sp = 0.f, sq = 0.f, sr = 0.f;
        #pragma unroll
        for (int c = 0; c < 64; ++c) {
            float w = V2[tid * 64 + c] * inv;
            sp += w * u[c]; sq += w * v[c]; sr += w * b1[c];
        }
        p[tid] = sp; q[tid] = sq; r[tid] = sr;
    }
    __syncthreads();

    const int n3 = tid & 31, og = tid >> 5;
    float nn = 0.f, mk = 0.f, mq = 0.f, mr = 0.f, mb = 0.f;
    #pragma unroll
    for (int i = 0; i < 16; ++i) {
        int o = og + 8 * i;
        float w = Vfc[k * 4096 + tid + 256 * i];
        nn += w * w;
        mk += w * p[o]; mq += w * q[o]; mr += w * r[o]; mb += w * b2[o];
    }
    #pragma unroll
    for (int off = 32; off; off >>= 1) nn += __shfl_xor(nn, off);
    if ((tid & 63) == 0) nnred[tid >> 6] = nn;
    redA[og][n3] = mk; redB[og][n3] = mq; redC[og][n3] = mr; redD[og][n3] = mb;
    __syncthreads();
    if (tid == 0) {
        float s = nnred[0] + nnred[1] + nnred[2] + nnred[3];
        scale_s = gfc[k] * rsqrtf(s);
    }
    __syncthreads();
    if (tid < 32) {
        float smk = 0.f, smq = 0.f, smr = 0.f, smb = 0.f;
        #pragma unroll
        for (int i = 0; i < 8; ++i) {
            smk += redA[i][tid]; smq += redB[i][tid];
            smr += redC[i][tid]; smb += redD[i][tid];
        }
        float scale = scale_s;
        M[tid] = scale * smk;
        float kcp = scale * (smq * T2[tid] + smr * cnt2[tid] + smb);
        #pragma unroll
        for (int off = 16; off; off >>= 1) kcp += __shfl_xor(kcp, off);
        if (tid == 0) Kc_s = kcp + bfc[k];
    }
    __syncthreads();
    if (tid < 32) {
        int b = tid;
        float s = 0.f;
        #pragma unroll
        for (int n = 0; n < 32; ++n) s += M[n] * S2[n * 32 + b];
        out[b * NCLS + k] = s + Kc_s;
    }
}

extern "C" void kernel_launch(void* const* d_in, const int* in_sizes, int n_in,
                              void* d_out, int out_size, void* d_ws, size_t ws_size,
                              hipStream_t stream) {
    const float* x   = (const float*)d_in[0];
    const int* src0  = (const int*)d_in[1];
    const int* dst0  = (const int*)d_in[2];
    const int* src1  = (const int*)d_in[3];
    const int* dst1  = (const int*)d_in[4];
    const int* src2  = (const int*)d_in[5];
    const int* dst2  = (const int*)d_in[6];
    const float* V0  = (const float*)d_in[7];
    const float* g0  = (const float*)d_in[8];
    const float* b0  = (const float*)d_in[9];
    const float* V1  = (const float*)d_in[10];
    const float* g1  = (const float*)d_in[11];
    const float* b1  = (const float*)d_in[12];
    const float* V2  = (const float*)d_in[13];
    const float* g2  = (const float*)d_in[14];
    const float* b2  = (const float*)d_in[15];
    const float* Vfc = (const float*)d_in[16];
    const float* gfc = (const float*)d_in[17];
    const float* bfc = (const float*)d_in[18];

    char* ws = (char*)d_ws;
    _Float16* xt  = (_Float16*)(ws);                 // 12,800,000 B
    int* esrc     = (int*)(ws + 12800000);           // 8,192,000 B
    int* off      = (int*)(ws + 20992000);           // 4,100 B (pad to 4,352)
    int* bstart   = (int*)(ws + 20996352);           // 20,480 B
    float* P0p    = (float*)(ws + 21016832);         // 524,288 B
    _Float16* P0h = (_Float16*)(ws + 21541120);      // 65,536 B
    _Float16* S1h = (_Float16*)(ws + 21606656);      // 16,384 B
    float* cnt1   = (float*)(ws + 21623040);         // 1,024 B
    float* S2     = (float*)(ws + 21624064);         // 4,096 B
    float* T2     = (float*)(ws + 21628160);         // 128 B
    float* cnt2   = (float*)(ws + 21628288);         // 128 B

    k_transpose<<<(N0 + 63) / 64, 256, 0, stream>>>(x, (h2*)xt);
    k_bounds<<<NE0 / 256, 256, 0, stream>>>(dst0, off);
    k_partition<<<N1, 256, 0, stream>>>(src0, off, esrc, bstart);
    k_gather0s<<<N1 * NB, 64, 0, stream>>>((const h8*)xt, esrc, bstart, P0p);
    k_reduceP<<<(N1 * 32) / 256, 256, 0, stream>>>(P0p, P0h);
    k_gather<<<N2, 256, 0, stream>>>((const h8*)P0h, src1, dst1, NE1,
                                     S1h, nullptr, nullptr, cnt1, nullptr);
    k_gather<<<N3, 256, 0, stream>>>((const h8*)S1h, src2, dst2, NE2,
                                     nullptr, S2, cnt1, cnt2, T2);
    k_out<<<NCLS, 256, 0, stream>>>(V0, g0, b0, V1, g1, b1, V2, g2, b2,
                                    Vfc, gfc, bfc, S2, T2, cnt2, (float*)d_out);
}